// Round 13
// baseline (630.487 us; speedup 1.0000x reference)
//
#include <hip/hip_runtime.h>

#define NN 100000
#define EE 1600000
#define CC 128
#define EPS 1e-5f
#define DMAX 64           // padded adjacency slots/node; P(Poisson(16) >= 64) ~ 2e-18

typedef __attribute__((ext_vector_type(8))) short sh8;
typedef __attribute__((ext_vector_type(4))) float fl4;

static __device__ __forceinline__ unsigned short f2bf(float f) {
    unsigned u = __float_as_uint(f);
    u = (u + 0x7fff + ((u >> 16) & 1)) >> 16;   // round-to-nearest-even
    return (unsigned short)u;
}
static __device__ __forceinline__ float bf2f(unsigned short s) {
    return __uint_as_float((unsigned)s << 16);
}

// ---------- padded adjacency build: ONE pass, no scan ----------
__global__ __launch_bounds__(256) void k_filld(const int* __restrict__ ei,
                                               int* __restrict__ cnt,
                                               int* __restrict__ colp) {
    int e = blockIdx.x * 256 + threadIdx.x;
    if (e < EE) {
        int d = ei[EE + e];
        int pos = atomicAdd(&cnt[d], 1);
        if (pos < DMAX) colp[(size_t)d * DMAX + pos] = ei[e];
    }
}

// ---------- x fp32 -> hA bf16 ----------
__global__ __launch_bounds__(256) void k_cvtx(const float* __restrict__ x,
                                              unsigned short* __restrict__ h) {
    int id = blockIdx.x * 256 + threadIdx.x;
    if (id >= NN * CC / 8) return;
    int row = id >> 4, g = id & 15;
    const float* xp = x + (size_t)row * CC + g * 8;
    unsigned short o[8];
#pragma unroll
    for (int e = 0; e < 8; ++e) o[e] = f2bf(xp[e]);
    *(sh8*)(h + (size_t)row * CC + g * 8) = *(sh8*)o;
}

// ---------- build Wfrag (layers): [lay][ks][nt][lane][8] ----------
__global__ __launch_bounds__(256) void k_wcvt(const float* __restrict__ Wl,
                                              const float* __restrict__ Wr,
                                              unsigned short* __restrict__ Wfrag) {
    int id = blockIdx.x * 256 + threadIdx.x;   // 16384
    if (id >= 16384) return;
    int lay = id >> 12;
    int rem = id & 4095;
    int ks = rem >> 9;
    int nt = (rem >> 6) & 7;
    int l = rem & 63;
    int c = nt * 16 + (l & 15);
    int kb = ks * 32 + (l >> 4) * 8;
    const float* WL = Wl + (size_t)lay * CC * CC;
    const float* WR = Wr + (size_t)lay * CC * CC;
    unsigned short o[8];
#pragma unroll
    for (int e = 0; e < 8; ++e) {
        int k = kb + e;
        float v = (k < 128) ? WL[(size_t)k * CC + c] : WR[(size_t)(k - 128) * CC + c];
        o[e] = f2bf(v);
    }
    *(sh8*)(Wfrag + (size_t)lay * 32768 + ks * 4096 + nt * 512 + l * 8) = *(sh8*)o;
}

// ---------- FUSED gather-mean + MFMA GEMM + BN + ReLU (+x) ----------
// 64 nodes/block, 4 waves. Phase A: wave wv gathers nodes [nbase+wv*16, +16)
// -> bf16 mean in mlds. Phase B: k_gemm MFMA body, A from mlds (ks<4) and
// global hin row (ks>=4). Writes hout (ping-pong -> no read/write race).
__global__ __launch_bounds__(256) void k_gg(
    const int* __restrict__ cnt, const int* __restrict__ colp,
    const unsigned short* __restrict__ hin,
    unsigned short* __restrict__ hout,
    const unsigned short* __restrict__ Wfrag,
    const float* __restrict__ bconv,
    const float* __restrict__ bng, const float* __restrict__ bnb,
    const float* __restrict__ bnm, const float* __restrict__ bnv,
    const float* __restrict__ x, int add_res)
{
    __shared__ unsigned short mlds[64][132];   // row stride 66 dwords == 2 mod 32
    const int t = threadIdx.x;
    const int w = t >> 6, l = t & 63;
    const int nbase = blockIdx.x * 64;

    // ---- Phase A: gather 16 nodes per wave (round-12 validated edge loop) ----
    {
        const int g = l & 15;
        const int par = l >> 4;
        const unsigned short* hbase = hin + g * 8;
#pragma unroll 1
        for (int i = 0; i < 16; ++i) {
            int node = nbase + w * 16 + i;
            float acc[8];
#pragma unroll
            for (int e = 0; e < 8; ++e) acc[e] = 0.f;
            if (node < NN) {
                const int* cl = colp + (size_t)node * DMAX;
                int c = cnt[node];
                if (c > DMAX) c = DMAX;
                int j = par;
                for (; j + 4 < c; j += 8) {
                    int s0 = cl[j];
                    int s1 = cl[j + 4];
                    sh8 v0 = *(const sh8*)(hbase + (size_t)s0 * CC);
                    sh8 v1 = *(const sh8*)(hbase + (size_t)s1 * CC);
#pragma unroll
                    for (int e = 0; e < 8; ++e) acc[e] += bf2f((unsigned short)v0[e]);
#pragma unroll
                    for (int e = 0; e < 8; ++e) acc[e] += bf2f((unsigned short)v1[e]);
                }
                if (j < c) {
                    int s0 = cl[j];
                    sh8 v0 = *(const sh8*)(hbase + (size_t)s0 * CC);
#pragma unroll
                    for (int e = 0; e < 8; ++e) acc[e] += bf2f((unsigned short)v0[e]);
                }
#pragma unroll
                for (int e = 0; e < 8; ++e) {
                    acc[e] += __shfl_xor(acc[e], 16);
                    acc[e] += __shfl_xor(acc[e], 32);
                }
                if (par == 0) {
                    float sc = 1.0f / fmaxf((float)c, 1.0f);
                    unsigned short o[8];
#pragma unroll
                    for (int e = 0; e < 8; ++e) o[e] = f2bf(acc[e] * sc);
                    *(sh8*)&mlds[w * 16 + i][g * 8] = *(sh8*)o;
                }
            }
        }
    }
    __syncthreads();

    // ---- Phase B: MFMA GEMM (round-3 validated body) ----
    const int rowbase = nbase + w * 16;
    int r_a = rowbase + (l & 15);
    if (r_a >= NN) r_a = NN - 1;
    const unsigned short* hrow = hin + (size_t)r_a * CC + (l >> 4) * 8;

    fl4 acc[8];
#pragma unroll
    for (int nt = 0; nt < 8; ++nt) acc[nt] = (fl4){0.f, 0.f, 0.f, 0.f};

#pragma unroll
    for (int ks = 0; ks < 8; ++ks) {
        sh8 a;
        if (ks < 4)
            a = *(const sh8*)&mlds[w * 16 + (l & 15)][ks * 32 + (l >> 4) * 8];
        else
            a = *(const sh8*)(hrow + (ks - 4) * 32);
        const unsigned short* wk = Wfrag + ks * 4096 + l * 8;
#pragma unroll
        for (int nt = 0; nt < 8; ++nt) {
            sh8 b = *(const sh8*)(wk + nt * 512);
            acc[nt] = __builtin_amdgcn_mfma_f32_16x16x32_bf16(a, b, acc[nt], 0, 0, 0);
        }
    }

    const int r0 = rowbase + (l >> 4) * 4;
#pragma unroll
    for (int nt = 0; nt < 8; ++nt) {
        int c = nt * 16 + (l & 15);
        float sc = bng[c] * rsqrtf(bnv[c] + EPS);
        float tt = (bconv[c] - bnm[c]) * sc + bnb[c];
#pragma unroll
        for (int j = 0; j < 4; ++j) {
            int row = r0 + j;
            if (row < NN) {
                float v = acc[nt][j] * sc + tt;
                v = fmaxf(v, 0.f);
                if (add_res) v += x[(size_t)row * CC + c];
                hout[(size_t)row * CC + c] = f2bf(v);
            }
        }
    }
}

// ---------- fused LN + fp32 tiled GEMM head: 32 nodes/block ----------
__global__ __launch_bounds__(256) void k_head2(
    const unsigned short* __restrict__ h,
    const float* __restrict__ lng, const float* __restrict__ lnb,
    const float* __restrict__ W1, const float* __restrict__ b1,
    const float* __restrict__ bog, const float* __restrict__ bob,
    const float* __restrict__ bom, const float* __restrict__ bov,
    const float* __restrict__ W2, const float* __restrict__ b2,
    float* __restrict__ out)
{
    __shared__ float Ws[128][68];   // W1 [k][n], padded
    __shared__ float hs[32][132];   // LN-normalized rows, padded
    const int t = threadIdx.x;
    const int nbase = blockIdx.x * 32;   // NN % 32 == 0 -> no tail guards

#pragma unroll
    for (int i = 0; i < 8; ++i) {
        int fi = (t + i * 256) * 4;
        int k = fi >> 6, j = fi & 63;
        *(float4*)&Ws[k][j] = *(const float4*)(W1 + fi);
    }

    const int lane = t & 63, wv = t >> 6;
#pragma unroll
    for (int i = 0; i < 8; ++i) {
        int nl = wv * 8 + i;
        const unsigned short* hp = h + (size_t)(nbase + nl) * CC;
        float v0 = bf2f(hp[lane]), v1 = bf2f(hp[lane + 64]);
        float s1 = v0 + v1, s2 = v0 * v0 + v1 * v1;
#pragma unroll
        for (int o = 32; o >= 1; o >>= 1) {
            s1 += __shfl_xor(s1, o);
            s2 += __shfl_xor(s2, o);
        }
        float mean = s1 * (1.0f / 128.0f);
        float var = s2 * (1.0f / 128.0f) - mean * mean;
        float rstd = rsqrtf(var + EPS);
        hs[nl][lane] = (v0 - mean) * rstd * lng[lane] + lnb[lane];
        hs[nl][lane + 64] = (v1 - mean) * rstd * lng[lane + 64] + lnb[lane + 64];
    }
    __syncthreads();

    const int tx = t & 15, ty = t >> 4;
    const int c0 = tx * 4, r0 = ty * 2;
    float acc[2][4] = {{0.f, 0.f, 0.f, 0.f}, {0.f, 0.f, 0.f, 0.f}};
#pragma unroll 4
    for (int k = 0; k < 128; k += 4) {
        float4 w0 = *(const float4*)&Ws[k][c0];
        float4 w1 = *(const float4*)&Ws[k + 1][c0];
        float4 w2v = *(const float4*)&Ws[k + 2][c0];
        float4 w3 = *(const float4*)&Ws[k + 3][c0];
#pragma unroll
        for (int i = 0; i < 2; ++i) {
            float4 a = *(const float4*)&hs[r0 + i][k];
            acc[i][0] += a.x * w0.x + a.y * w1.x + a.z * w2v.x + a.w * w3.x;
            acc[i][1] += a.x * w0.y + a.y * w1.y + a.z * w2v.y + a.w * w3.y;
            acc[i][2] += a.x * w0.z + a.y * w1.z + a.z * w2v.z + a.w * w3.z;
            acc[i][3] += a.x * w0.w + a.y * w1.w + a.z * w2v.w + a.w * w3.w;
        }
    }

    float rr[2] = {0.f, 0.f};
#pragma unroll
    for (int jc = 0; jc < 4; ++jc) {
        int c = c0 + jc;
        float sc = bog[c] * rsqrtf(bov[c] + EPS);
        float tt = (b1[c] - bom[c]) * sc + bob[c];
        float w2 = W2[c];
#pragma unroll
        for (int i = 0; i < 2; ++i) {
            float v = acc[i][jc] * sc + tt;
            v = fmaxf(v, 0.f);
            rr[i] += v * w2;
        }
    }
#pragma unroll
    for (int i = 0; i < 2; ++i) {
        rr[i] += __shfl_xor(rr[i], 1);
        rr[i] += __shfl_xor(rr[i], 2);
        rr[i] += __shfl_xor(rr[i], 4);
        rr[i] += __shfl_xor(rr[i], 8);
    }
    if (tx == 0) {
        float bb = b2[0];
        out[nbase + r0] = rr[0] + bb;
        out[nbase + r0 + 1] = rr[1] + bb;
    }
}

extern "C" void kernel_launch(void* const* d_in, const int* in_sizes, int n_in,
                              void* d_out, int out_size, void* d_ws, size_t ws_size,
                              hipStream_t stream) {
    const float* x     = (const float*)d_in[0];
    const int*   ei    = (const int*)d_in[1];
    const float* Wl    = (const float*)d_in[2];
    const float* Wr    = (const float*)d_in[3];
    const float* bconv = (const float*)d_in[4];
    const float* bng   = (const float*)d_in[5];
    const float* bnb   = (const float*)d_in[6];
    const float* bnm   = (const float*)d_in[7];
    const float* bnv   = (const float*)d_in[8];
    const float* lng   = (const float*)d_in[9];
    const float* lnb   = (const float*)d_in[10];
    const float* W1    = (const float*)d_in[11];
    const float* b1    = (const float*)d_in[12];
    const float* bog   = (const float*)d_in[13];
    const float* bob   = (const float*)d_in[14];
    const float* bom   = (const float*)d_in[15];
    const float* bov   = (const float*)d_in[16];
    const float* W2    = (const float*)d_in[17];
    const float* b2    = (const float*)d_in[18];

    unsigned short* hA    = (unsigned short*)d_ws;            // N*128 bf16
    unsigned short* hB    = hA + (size_t)NN * CC;             // N*128 bf16
    unsigned short* Wfrag = hB + (size_t)NN * CC;             // 4*32768 bf16
    int*   cnt  = (int*)(Wfrag + 4 * 32768);                  // N
    int*   colp = cnt + NN;                                   // N*DMAX

    hipMemsetAsync(cnt, 0, NN * sizeof(int), stream);
    k_cvtx<<<(NN * CC / 8 + 255) / 256, 256, 0, stream>>>(x, hA);
    k_wcvt<<<64, 256, 0, stream>>>(Wl, Wr, Wfrag);
    k_filld<<<(EE + 255) / 256, 256, 0, stream>>>(ei, cnt, colp);

    const unsigned short* hin = hA;
    unsigned short* houts[4] = {hB, hA, hB, hA};
    for (int l = 0; l < 4; ++l) {
        k_gg<<<(NN + 63) / 64, 256, 0, stream>>>(
            cnt, colp, hin, houts[l], Wfrag + (size_t)l * 32768,
            bconv + l * CC, bng + l * CC, bnb + l * CC, bnm + l * CC, bnv + l * CC,
            x, (l == 0) ? 1 : 0);
        hin = houts[l];
    }
    k_head2<<<NN / 32, 256, 0, stream>>>(hA, lng, lnb, W1, b1,
                                         bog, bob, bom, bov, W2, b2, (float*)d_out);
}

// Round 14
// 552.073 us; speedup vs baseline: 1.1420x; 1.1420x over previous
//
#include <hip/hip_runtime.h>

#define NN 100000
#define EE 1600000
#define CC 128
#define EPS 1e-5f
#define DMAX 64           // padded adjacency slots/node; P(Poisson(16) >= 64) ~ 2e-18

typedef __attribute__((ext_vector_type(8))) short sh8;
typedef __attribute__((ext_vector_type(4))) float fl4;

static __device__ __forceinline__ unsigned short f2bf(float f) {
    unsigned u = __float_as_uint(f);
    u = (u + 0x7fff + ((u >> 16) & 1)) >> 16;   // round-to-nearest-even
    return (unsigned short)u;
}
static __device__ __forceinline__ float bf2f(unsigned short s) {
    return __uint_as_float((unsigned)s << 16);
}

// ---------- padded adjacency build: ONE pass, no scan ----------
__global__ __launch_bounds__(256) void k_filld(const int* __restrict__ ei,
                                               int* __restrict__ cnt,
                                               int* __restrict__ colp) {
    int e = blockIdx.x * 256 + threadIdx.x;
    if (e < EE) {
        int d = ei[EE + e];
        int pos = atomicAdd(&cnt[d], 1);
        if (pos < DMAX) colp[(size_t)d * DMAX + pos] = ei[e];
    }
}

// ---------- merged prologue: blocks [0,6250) cvtx; [6250,6314) wcvt ----------
__global__ __launch_bounds__(256) void k_prep(const float* __restrict__ x,
                                              unsigned short* __restrict__ A2,
                                              const float* __restrict__ Wl,
                                              const float* __restrict__ Wr,
                                              unsigned short* __restrict__ Wfrag) {
    const int b = blockIdx.x;
    if (b < (NN * CC / 8) / 256) {
        // x fp32 -> A2 h-columns bf16
        int id = b * 256 + threadIdx.x;
        int row = id >> 4, g = id & 15;
        const float* xp = x + (size_t)row * CC + g * 8;
        unsigned short o[8];
#pragma unroll
        for (int e = 0; e < 8; ++e) o[e] = f2bf(xp[e]);
        *(sh8*)(A2 + (size_t)row * 256 + 128 + g * 8) = *(sh8*)o;
    } else {
        // build Wfrag: [lay][ks][nt][lane][8]
        int id = (b - (NN * CC / 8) / 256) * 256 + threadIdx.x;   // 16384
        if (id >= 16384) return;
        int lay = id >> 12;
        int rem = id & 4095;
        int ks = rem >> 9;
        int nt = (rem >> 6) & 7;
        int l = rem & 63;
        int c = nt * 16 + (l & 15);
        int kb = ks * 32 + (l >> 4) * 8;
        const float* WL = Wl + (size_t)lay * CC * CC;
        const float* WR = Wr + (size_t)lay * CC * CC;
        unsigned short o[8];
#pragma unroll
        for (int e = 0; e < 8; ++e) {
            int k = kb + e;
            float v = (k < 128) ? WL[(size_t)k * CC + c] : WR[(size_t)(k - 128) * CC + c];
            o[e] = f2bf(v);
        }
        *(sh8*)(Wfrag + (size_t)lay * 32768 + ks * 4096 + nt * 512 + l * 8) = *(sh8*)o;
    }
}

// ---------- gather-mean (bf16): wave/node, padded adjacency, 2x unroll ----------
__global__ __launch_bounds__(256) void k_gather(const int* __restrict__ cnt,
                                                const int* __restrict__ colp,
                                                unsigned short* __restrict__ A2) {
    int node = blockIdx.x * 4 + (threadIdx.x >> 6);
    if (node >= NN) return;
    int lane = threadIdx.x & 63;
    int g = lane & 15;
    int par = lane >> 4;
    const unsigned short* hbase = A2 + 128 + g * 8;
    const int* cl = colp + (size_t)node * DMAX;
    int c = cnt[node];
    if (c > DMAX) c = DMAX;
    float acc[8];
#pragma unroll
    for (int e = 0; e < 8; ++e) acc[e] = 0.f;
    int j = par;
    for (; j + 4 < c; j += 8) {
        int s0 = cl[j];
        int s1 = cl[j + 4];
        sh8 v0 = *(const sh8*)(hbase + (size_t)s0 * 256);
        sh8 v1 = *(const sh8*)(hbase + (size_t)s1 * 256);
#pragma unroll
        for (int e = 0; e < 8; ++e) acc[e] += bf2f((unsigned short)v0[e]);
#pragma unroll
        for (int e = 0; e < 8; ++e) acc[e] += bf2f((unsigned short)v1[e]);
    }
    if (j < c) {
        int s0 = cl[j];
        sh8 v0 = *(const sh8*)(hbase + (size_t)s0 * 256);
#pragma unroll
        for (int e = 0; e < 8; ++e) acc[e] += bf2f((unsigned short)v0[e]);
    }
#pragma unroll
    for (int e = 0; e < 8; ++e) {
        acc[e] += __shfl_xor(acc[e], 16);
        acc[e] += __shfl_xor(acc[e], 32);
    }
    if (par == 0) {
        float sc = 1.0f / fmaxf((float)c, 1.0f);   // exact IEEE divide
        unsigned short o[8];
#pragma unroll
        for (int e = 0; e < 8; ++e) o[e] = f2bf(acc[e] * sc);
        *(sh8*)(A2 + (size_t)node * 256 + g * 8) = *(sh8*)o;
    }
}

// ---------- MFMA GEMM: A2 @ Wfrag -> BN+ReLU(+x) -> A2 h-cols ----------
__global__ __launch_bounds__(256) void k_gemm(
    const unsigned short* __restrict__ A2w,
    unsigned short* __restrict__ A2,
    const unsigned short* __restrict__ Wfrag,
    const float* __restrict__ bconv,
    const float* __restrict__ bng, const float* __restrict__ bnb,
    const float* __restrict__ bnm, const float* __restrict__ bnv,
    const float* __restrict__ x, int add_res)
{
    const int t = threadIdx.x;
    const int w = t >> 6, l = t & 63;
    const int rowbase = blockIdx.x * 64 + w * 16;
    int r_a = rowbase + (l & 15);
    if (r_a >= NN) r_a = NN - 1;
    const unsigned short* arow = A2w + (size_t)r_a * 256 + (l >> 4) * 8;

    fl4 acc[8];
#pragma unroll
    for (int nt = 0; nt < 8; ++nt) acc[nt] = (fl4){0.f, 0.f, 0.f, 0.f};

#pragma unroll
    for (int ks = 0; ks < 8; ++ks) {
        sh8 a = *(const sh8*)(arow + ks * 32);
        const unsigned short* wk = Wfrag + ks * 4096 + l * 8;
#pragma unroll
        for (int nt = 0; nt < 8; ++nt) {
            sh8 b = *(const sh8*)(wk + nt * 512);
            acc[nt] = __builtin_amdgcn_mfma_f32_16x16x32_bf16(a, b, acc[nt], 0, 0, 0);
        }
    }

    const int r0 = rowbase + (l >> 4) * 4;
#pragma unroll
    for (int nt = 0; nt < 8; ++nt) {
        int c = nt * 16 + (l & 15);
        float sc = bng[c] * rsqrtf(bnv[c] + EPS);
        float tt = (bconv[c] - bnm[c]) * sc + bnb[c];
#pragma unroll
        for (int j = 0; j < 4; ++j) {
            int row = r0 + j;
            if (row < NN) {
                float v = acc[nt][j] * sc + tt;
                v = fmaxf(v, 0.f);
                if (add_res) v += x[(size_t)row * CC + c];
                A2[(size_t)row * 256 + 128 + c] = f2bf(v);
            }
        }
    }
}

// ---------- fused LN + fp32 tiled GEMM head: 32 nodes/block ----------
__global__ __launch_bounds__(256) void k_head2(
    const unsigned short* __restrict__ A2,
    const float* __restrict__ lng, const float* __restrict__ lnb,
    const float* __restrict__ W1, const float* __restrict__ b1,
    const float* __restrict__ bog, const float* __restrict__ bob,
    const float* __restrict__ bom, const float* __restrict__ bov,
    const float* __restrict__ W2, const float* __restrict__ b2,
    float* __restrict__ out)
{
    __shared__ float Ws[128][68];   // W1 [k][n], padded
    __shared__ float hs[32][132];   // LN-normalized rows, padded
    const int t = threadIdx.x;
    const int nbase = blockIdx.x * 32;   // NN % 32 == 0 -> no tail guards

#pragma unroll
    for (int i = 0; i < 8; ++i) {
        int fi = (t + i * 256) * 4;
        int k = fi >> 6, j = fi & 63;
        *(float4*)&Ws[k][j] = *(const float4*)(W1 + fi);
    }

    const int lane = t & 63, wv = t >> 6;
#pragma unroll
    for (int i = 0; i < 8; ++i) {
        int nl = wv * 8 + i;
        const unsigned short* hp = A2 + (size_t)(nbase + nl) * 256 + 128;
        float v0 = bf2f(hp[lane]), v1 = bf2f(hp[lane + 64]);
        float s1 = v0 + v1, s2 = v0 * v0 + v1 * v1;
#pragma unroll
        for (int o = 32; o >= 1; o >>= 1) {
            s1 += __shfl_xor(s1, o);
            s2 += __shfl_xor(s2, o);
        }
        float mean = s1 * (1.0f / 128.0f);
        float var = s2 * (1.0f / 128.0f) - mean * mean;
        float rstd = rsqrtf(var + EPS);
        hs[nl][lane] = (v0 - mean) * rstd * lng[lane] + lnb[lane];
        hs[nl][lane + 64] = (v1 - mean) * rstd * lng[lane + 64] + lnb[lane + 64];
    }
    __syncthreads();

    const int tx = t & 15, ty = t >> 4;
    const int c0 = tx * 4, r0 = ty * 2;
    float acc[2][4] = {{0.f, 0.f, 0.f, 0.f}, {0.f, 0.f, 0.f, 0.f}};
#pragma unroll 4
    for (int k = 0; k < 128; k += 4) {
        float4 w0 = *(const float4*)&Ws[k][c0];
        float4 w1 = *(const float4*)&Ws[k + 1][c0];
        float4 w2v = *(const float4*)&Ws[k + 2][c0];
        float4 w3 = *(const float4*)&Ws[k + 3][c0];
#pragma unroll
        for (int i = 0; i < 2; ++i) {
            float4 a = *(const float4*)&hs[r0 + i][k];
            acc[i][0] += a.x * w0.x + a.y * w1.x + a.z * w2v.x + a.w * w3.x;
            acc[i][1] += a.x * w0.y + a.y * w1.y + a.z * w2v.y + a.w * w3.y;
            acc[i][2] += a.x * w0.z + a.y * w1.z + a.z * w2v.z + a.w * w3.z;
            acc[i][3] += a.x * w0.w + a.y * w1.w + a.z * w2v.w + a.w * w3.w;
        }
    }

    float rr[2] = {0.f, 0.f};
#pragma unroll
    for (int jc = 0; jc < 4; ++jc) {
        int c = c0 + jc;
        float sc = bog[c] * rsqrtf(bov[c] + EPS);
        float tt = (b1[c] - bom[c]) * sc + bob[c];
        float w2 = W2[c];
#pragma unroll
        for (int i = 0; i < 2; ++i) {
            float v = acc[i][jc] * sc + tt;
            v = fmaxf(v, 0.f);
            rr[i] += v * w2;
        }
    }
#pragma unroll
    for (int i = 0; i < 2; ++i) {
        rr[i] += __shfl_xor(rr[i], 1);
        rr[i] += __shfl_xor(rr[i], 2);
        rr[i] += __shfl_xor(rr[i], 4);
        rr[i] += __shfl_xor(rr[i], 8);
    }
    if (tx == 0) {
        float bb = b2[0];
        out[nbase + r0] = rr[0] + bb;
        out[nbase + r0 + 1] = rr[1] + bb;
    }
}

extern "C" void kernel_launch(void* const* d_in, const int* in_sizes, int n_in,
                              void* d_out, int out_size, void* d_ws, size_t ws_size,
                              hipStream_t stream) {
    const float* x     = (const float*)d_in[0];
    const int*   ei    = (const int*)d_in[1];
    const float* Wl    = (const float*)d_in[2];
    const float* Wr    = (const float*)d_in[3];
    const float* bconv = (const float*)d_in[4];
    const float* bng   = (const float*)d_in[5];
    const float* bnb   = (const float*)d_in[6];
    const float* bnm   = (const float*)d_in[7];
    const float* bnv   = (const float*)d_in[8];
    const float* lng   = (const float*)d_in[9];
    const float* lnb   = (const float*)d_in[10];
    const float* W1    = (const float*)d_in[11];
    const float* b1    = (const float*)d_in[12];
    const float* bog   = (const float*)d_in[13];
    const float* bob   = (const float*)d_in[14];
    const float* bom   = (const float*)d_in[15];
    const float* bov   = (const float*)d_in[16];
    const float* W2    = (const float*)d_in[17];
    const float* b2    = (const float*)d_in[18];

    unsigned short* A2    = (unsigned short*)d_ws;            // N*256 bf16
    unsigned short* Wfrag = A2 + (size_t)NN * 256;            // 4*32768 bf16
    int*   cnt  = (int*)(Wfrag + 4 * 32768);                  // N
    int*   colp = cnt + NN;                                   // N*DMAX

    hipMemsetAsync(cnt, 0, NN * sizeof(int), stream);
    k_prep<<<(NN * CC / 8) / 256 + 64, 256, 0, stream>>>(x, A2, Wl, Wr, Wfrag);
    k_filld<<<(EE + 255) / 256, 256, 0, stream>>>(ei, cnt, colp);

    for (int l = 0; l < 4; ++l) {
        k_gather<<<(NN + 3) / 4, 256, 0, stream>>>(cnt, colp, A2);
        k_gemm<<<(NN + 63) / 64, 256, 0, stream>>>(
            A2, A2, Wfrag + (size_t)l * 32768,
            bconv + l * CC, bng + l * CC, bnb + l * CC, bnm + l * CC, bnv + l * CC,
            x, (l == 0) ? 1 : 0);
    }
    k_head2<<<NN / 32, 256, 0, stream>>>(A2, lng, lnb, W1, b1,
                                         bog, bob, bom, bov, W2, b2, (float*)d_out);
}